// Round 1
// baseline (339.747 us; speedup 1.0000x reference)
//
#include <hip/hip_runtime.h>
#include <type_traits>
#include <utility>

// ---------------- problem constants ----------------
#define B_    8
#define NQ_   1024
#define I_    21760      // 128*128 + 64*64 + 32*32 + 16*16
#define EMB_  256
#define HID_  256
#define H_    8
#define CH_   32

typedef float  f32x4  __attribute__((ext_vector_type(4)));
typedef __bf16 bf16x8 __attribute__((ext_vector_type(8)));
typedef short  s16x8  __attribute__((ext_vector_type(8)));

// ---- MFMA shim: works whether the builtin wants v8bf16 or v8i16 ----
template <typename V, typename = void>
struct bf16_mfma_native : std::false_type {};
template <typename V>
struct bf16_mfma_native<V, std::void_t<decltype(__builtin_amdgcn_mfma_f32_16x16x32_bf16(
    std::declval<V>(), std::declval<V>(), std::declval<f32x4>(), 0, 0, 0))>>
    : std::true_type {};

template <typename V>
__device__ __forceinline__ f32x4 mfma_dispatch(V a, V b, f32x4 c) {
  if constexpr (bf16_mfma_native<V>::value) {
    return __builtin_amdgcn_mfma_f32_16x16x32_bf16(a, b, c, 0, 0, 0);
  } else {
    return __builtin_amdgcn_mfma_f32_16x16x32_bf16(
        __builtin_bit_cast(s16x8, a), __builtin_bit_cast(s16x8, b), c, 0, 0, 0);
  }
}

__device__ __forceinline__ f32x4 MFMA(s16x8 a, s16x8 b, f32x4 c) {
  return mfma_dispatch(__builtin_bit_cast(bf16x8, a), __builtin_bit_cast(bf16x8, b), c);
}

// float -> bf16 bits, round-to-nearest-even
__device__ __forceinline__ unsigned short f2bf(float f) {
  unsigned u = __float_as_uint(f);
  u += 0x7fffu + ((u >> 16) & 1u);
  return (unsigned short)(u >> 16);
}

// ---------------------------------------------------------------
// Generic GEMM, K fixed = 256:  Out[M,N] = A[M,256] @ W[256,N] + bias
// 512 threads = 8 waves. Wave w owns columns {s*128 + w*16 .. +15}.
// W strip in registers. A tile (32 x 256) staged fp32->bf16 in LDS
// (row stride 264). Register prefetch of the next A tile is issued
// right after the first barrier so HBM latency hides under MFMA.
// OUTM: 0 = fp32 linear [M][N], 1 = bf16 head-major [(b*8+h)][i][32]
// ---------------------------------------------------------------
template <int NS, int OUTM>
__global__ __launch_bounds__(512) void gemm_k256(
    const float* __restrict__ A, const float* __restrict__ W,
    const float* __restrict__ bias, void* __restrict__ Out,
    const int N, const int Mtiles) {
  __shared__ __align__(16) short lds[32 * 264];
  const int tid  = threadIdx.x;
  const int lane = tid & 63;
  const int wave = tid >> 6;
  const int quad = lane >> 4;
  const int ln   = lane & 15;

  // --- load W fragments (one-time, strided; L2-resident) ---
  s16x8 bfrag[NS][8];
  float bv[NS];
#pragma unroll
  for (int st = 0; st < NS; ++st) {
    const int ng = st * 128 + wave * 16 + ln;
    bv[st] = bias[ng];
#pragma unroll
    for (int ks = 0; ks < 8; ++ks) {
      s16x8 f;
#pragma unroll
      for (int j = 0; j < 8; ++j)
        f[j] = (short)f2bf(W[(ks * 32 + quad * 8 + j) * N + ng]);
      bfrag[st][ks] = f;
    }
  }

  const int sr = tid >> 4;          // staging row 0..31
  const int sc = (tid & 15) * 16;   // staging col (16 floats per thread)

  int t = blockIdx.x;
  float4 v0, v1, v2, v3;
  if (t < Mtiles) {
    const float4* src = (const float4*)(A + ((size_t)t * 32 + sr) * 256 + sc);
    v0 = src[0]; v1 = src[1]; v2 = src[2]; v3 = src[3];
  }

  for (; t < Mtiles; t += gridDim.x) {
    // --- pack the prefetched tile fp32 -> bf16 into LDS ---
    {
      s16x8 p0, p1;
      p0[0] = (short)f2bf(v0.x); p0[1] = (short)f2bf(v0.y);
      p0[2] = (short)f2bf(v0.z); p0[3] = (short)f2bf(v0.w);
      p0[4] = (short)f2bf(v1.x); p0[5] = (short)f2bf(v1.y);
      p0[6] = (short)f2bf(v1.z); p0[7] = (short)f2bf(v1.w);
      p1[0] = (short)f2bf(v2.x); p1[1] = (short)f2bf(v2.y);
      p1[2] = (short)f2bf(v2.z); p1[3] = (short)f2bf(v2.w);
      p1[4] = (short)f2bf(v3.x); p1[5] = (short)f2bf(v3.y);
      p1[6] = (short)f2bf(v3.z); p1[7] = (short)f2bf(v3.w);
      *(s16x8*)&lds[sr * 264 + sc]     = p0;
      *(s16x8*)&lds[sr * 264 + sc + 8] = p1;
    }
    __syncthreads();

    // --- issue next tile's loads NOW; they complete under the MFMAs ---
    {
      const int tn = t + gridDim.x;
      if (tn < Mtiles) {
        const float4* src = (const float4*)(A + ((size_t)tn * 32 + sr) * 256 + sc);
        v0 = src[0]; v1 = src[1]; v2 = src[2]; v3 = src[3];
      }
    }

    f32x4 acc[NS][2];
#pragma unroll
    for (int st = 0; st < NS; ++st) {
      acc[st][0] = f32x4{bv[st], bv[st], bv[st], bv[st]};
      acc[st][1] = acc[st][0];
    }
#pragma unroll
    for (int ks = 0; ks < 8; ++ks) {
      s16x8 a0 = *(const s16x8*)&lds[ln * 264 + ks * 32 + quad * 8];
      s16x8 a1 = *(const s16x8*)&lds[(ln + 16) * 264 + ks * 32 + quad * 8];
#pragma unroll
      for (int st = 0; st < NS; ++st) {
        acc[st][0] = MFMA(a0, bfrag[st][ks], acc[st][0]);
        acc[st][1] = MFMA(a1, bfrag[st][ks], acc[st][1]);
      }
    }
    // --- epilogue: D[m = quad*4+reg][n = ln] ---
    const size_t rowBase = (size_t)t * 32;
    if constexpr (OUTM == 1) {
      // bf16 head-major: [(b*8 + h)][i][32]; tiles never cross b (I_%32==0)
      const int tb  = (int)(rowBase / I_);
      const int ir0 = (int)(rowBase - (size_t)tb * I_);
      unsigned short* O = (unsigned short*)Out;
#pragma unroll
      for (int st = 0; st < NS; ++st) {
        const int ng = st * 128 + wave * 16 + ln;
        const int hh = ng >> 5, cc = ng & 31;
        const size_t pl = (size_t)(tb * 8 + hh) * I_;
#pragma unroll
        for (int rt = 0; rt < 2; ++rt) {
#pragma unroll
          for (int r = 0; r < 4; ++r) {
            const size_t i = pl + (size_t)(ir0 + rt * 16 + quad * 4 + r);
            O[i * 32 + cc] = f2bf(acc[st][rt][r]);
          }
        }
      }
    } else {
      float* O = (float*)Out;
#pragma unroll
      for (int st = 0; st < NS; ++st) {
        const int ng = st * 128 + wave * 16 + ln;
#pragma unroll
        for (int rt = 0; rt < 2; ++rt) {
#pragma unroll
          for (int r = 0; r < 4; ++r) {
            const size_t m = rowBase + rt * 16 + quad * 4 + r;
            O[m * N + ng] = acc[st][rt][r];
          }
        }
      }
    }
    __syncthreads();
  }
}

// ---------------------------------------------------------------
// Fused softmax + sampling-point + MSDA bilinear gather.
// 1 block (128 thr) per (b,n), batch-grouped on XCDs.
// Phase A: thread (h,lp) does the 16-wide softmax via shfl_xor,
//   folds the 4 bilinear corners into 2 contiguous x-PAIRS
//   (head-major imgp: pair = 128 contiguous bytes) -> LDS.
// Phase B: thread (h,c2): p=c2>>3 picks pair element, 8 threads
//   cover a 64B pixel slice with uint2 loads; shfl_xor(8) combines
//   the two pair halves; each thread stores float2.
// ---------------------------------------------------------------
__global__ __launch_bounds__(128) void msda_fused_kernel(
    const unsigned int* __restrict__ imgp,  // bf16 pairs, head-major [(b*8+h)*I_][16] uints
    const float* __restrict__ qp, const float* __restrict__ refp,
    float* __restrict__ out) {
  __shared__ __align__(16) float sw[128][4];
  __shared__ __align__(16) int   sib[128][2];
  // bijective XCD swizzle: consecutive hw blocks 0..7 -> b=0..7, so each
  // XCD's L2 sees one batch's 11 MB instead of all 89 MB.
  const int bid = ((blockIdx.x & 7) << 10) | (blockIdx.x >> 3);
  const int b   = bid >> 10;
  const int tid = threadIdx.x;

  {
    const int h = tid >> 4, lp = tid & 15, l = lp >> 2;
    const int ww = 128 >> l;                              // square levels
    const int start = (65536 - (65536 >> (2 * l))) / 3;   // 0,16384,20480,21504
    const float invsh = __uint_as_float((unsigned)(120 + l) << 23);  // 1/ww exactly

    const float* qb = qp + (size_t)bid * 384 + h * 48 + lp * 3;
    const float ox = qb[0], oy = qb[1], z = qb[2];
    // softmax over the 16 lanes of this (q,h) group
    float m = z;
    m = fmaxf(m, __shfl_xor(m, 1, 16));
    m = fmaxf(m, __shfl_xor(m, 2, 16));
    m = fmaxf(m, __shfl_xor(m, 4, 16));
    m = fmaxf(m, __shfl_xor(m, 8, 16));
    float e = __expf(z - m);
    float s = e;
    s += __shfl_xor(s, 1, 16);
    s += __shfl_xor(s, 2, 16);
    s += __shfl_xor(s, 4, 16);
    s += __shfl_xor(s, 8, 16);
    const float a = e / s;

    const float rx = refp[bid * 2], ry = refp[bid * 2 + 1];
    const float x = (rx + ox * invsh) * (float)ww - 0.5f;
    const float y = (ry + oy * invsh) * (float)ww - 0.5f;
    const float x0f = floorf(x), y0f = floorf(y);
    const float wx = x - x0f, wy = y - y0f;
    const int x0 = (int)x0f, y0 = (int)y0f;

    // fold x-corners onto the contiguous pair (xb, xb+1)
    const int xb = min(max(x0, 0), ww - 2);
    float u0 = 0.f, u1 = 0.f;
    if (x0 >= 0 && x0 < ww)         { if (x0 == xb)     u0 += 1.f - wx; else u1 += 1.f - wx; }
    if (x0 + 1 >= 0 && x0 + 1 < ww) { if (x0 + 1 == xb) u0 += wx;       else u1 += wx; }
    const float wy0 = (y0 >= 0     && y0 < ww)     ? a * (1.f - wy) : 0.f;
    const float wy1 = (y0 + 1 >= 0 && y0 + 1 < ww) ? a * wy         : 0.f;
    const int yc0 = min(max(y0, 0), ww - 1);
    const int yc1 = min(max(y0 + 1, 0), ww - 1);

    const int pb = (b * 8 + h) * I_ + start + xb;
    sw[tid][0] = wy0 * u0; sw[tid][1] = wy0 * u1;
    sw[tid][2] = wy1 * u0; sw[tid][3] = wy1 * u1;
    sib[tid][0] = (pb + yc0 * ww) * 16;   // uint (bf16-pair) units
    sib[tid][1] = (pb + yc1 * ww) * 16;
  }
  __syncthreads();

  const int h = tid >> 4, c2 = tid & 15;
  const int p  = c2 >> 3;                    // which pixel of the x-pair
  const int cp = ((c2 & 7) << 1) + (p << 4); // uint offset: pair element + channel pair
  float a0 = 0.f, a1 = 0.f, a2 = 0.f, a3 = 0.f;
#pragma unroll
  for (int lp = 0; lp < 16; ++lp) {
    const float4 w4 = *(const float4*)sw[h * 16 + lp];   // LDS broadcast
    const int2   ib = *(const int2*)sib[h * 16 + lp];
    const float w0 = p ? w4.y : w4.x;   // row y0 weight for my pixel
    const float w1 = p ? w4.w : w4.z;   // row y1 weight for my pixel
    const uint2 ua = *(const uint2*)&imgp[ib.x + cp];
    const uint2 ub = *(const uint2*)&imgp[ib.y + cp];
    a0 += w0 * __uint_as_float(ua.x << 16);
    a1 += w0 * __uint_as_float(ua.x & 0xffff0000u);
    a2 += w0 * __uint_as_float(ua.y << 16);
    a3 += w0 * __uint_as_float(ua.y & 0xffff0000u);
    a0 += w1 * __uint_as_float(ub.x << 16);
    a1 += w1 * __uint_as_float(ub.x & 0xffff0000u);
    a2 += w1 * __uint_as_float(ub.y << 16);
    a3 += w1 * __uint_as_float(ub.y & 0xffff0000u);
  }
  // combine the two halves of the x-pair (lanes c2 and c2^8, same h)
  a0 += __shfl_xor(a0, 8);
  a1 += __shfl_xor(a1, 8);
  a2 += __shfl_xor(a2, 8);
  a3 += __shfl_xor(a3, 8);
  float2 r;
  r.x = p ? a2 : a0;
  r.y = p ? a3 : a1;
  *(float2*)&out[(size_t)bid * 256 + h * 32 + ((c2 & 7) << 2) + (p << 1)] = r;
}

// ---------------------------------------------------------------
// workspace layout (bytes)
// ---------------------------------------------------------------
#define OFF_IMGP 0ULL                        // 8*8*21760*32*2 = 89,128,960 (bf16, head-major)
#define OFF_QP   89128960ULL                 // 8192*384*4     = 12,582,912
#define OFF_MSDA 101711872ULL                // 8192*256*4     =  8,388,608
#define WS_NEEDED 110100480ULL

extern "C" void kernel_launch(void* const* d_in, const int* in_sizes, int n_in,
                              void* d_out, int out_size, void* d_ws, size_t ws_size,
                              hipStream_t stream) {
  const float* img     = (const float*)d_in[0];
  const float* queries = (const float*)d_in[2];
  const float* refp    = (const float*)d_in[3];
  const float* W_img   = (const float*)d_in[4];
  const float* b_img   = (const float*)d_in[5];
  const float* W_q     = (const float*)d_in[6];
  const float* b_q     = (const float*)d_in[7];
  const float* W_out   = (const float*)d_in[8];
  const float* b_out   = (const float*)d_in[9];

  if (ws_size < WS_NEEDED) return;  // workspace too small -> fail loudly

  char* ws = (char*)d_ws;
  unsigned short* imgp = (unsigned short*)(ws + OFF_IMGP);
  float* qp   = (float*)(ws + OFF_QP);
  float* msda = (float*)(ws + OFF_MSDA);

  // img_p = img @ W_img + b_img   (174080 x 256) -> bf16 head-major [(b,h)][i][ch]
  hipLaunchKernelGGL((gemm_k256<2, 1>), dim3(512), dim3(512), 0, stream,
                     img, W_img, b_img, (void*)imgp, 256, I_ * B_ / 32);
  // qp = queries @ W_q + b_q      (8192 x 384) -> fp32
  hipLaunchKernelGGL((gemm_k256<3, 0>), dim3(256), dim3(512), 0, stream,
                     queries, W_q, b_q, (void*)qp, 384, B_ * NQ_ / 32);
  // fused softmax + sampling + bilinear gather
  hipLaunchKernelGGL(msda_fused_kernel, dim3(B_ * NQ_), dim3(128), 0, stream,
                     (const unsigned int*)imgp, qp, refp, msda);
  // out = msda @ W_out + b_out    (8192 x 256) -> fp32
  hipLaunchKernelGGL((gemm_k256<2, 0>), dim3(256), dim3(512), 0, stream,
                     msda, W_out, b_out, d_out, 256, B_ * NQ_ / 32);
}